// Round 13
// baseline (699.620 us; speedup 1.0000x reference)
//
#include <hip/hip_runtime.h>

#define NN 50000
#define MPAD 50048
#define EE 800000
#define ETOT (EE + NN)
#define IN_DIM 128
#define EDGE_DIM 32
#define EMB 256
#define HH 8
#define LL 4
#define NEG_SLOPE 0.2f

typedef __attribute__((ext_vector_type(8))) short bf16x8;
typedef __attribute__((ext_vector_type(4))) float f32x4;

__device__ inline ushort f2bf_rn(float x) {
    union { float f; uint u; } v; v.f = x;
    uint r = v.u + 0x7FFFu + ((v.u >> 16) & 1u);
    return (ushort)(r >> 16);
}
__device__ inline float bf2f(ushort b) {
    union { uint u; float f; } v; v.u = ((uint)b) << 16;
    return v.f;
}

__device__ __forceinline__ void g2l16(const void* g, void* l) {
    __builtin_amdgcn_global_load_lds((const __attribute__((address_space(1))) void*)g,
                                     (__attribute__((address_space(3))) void*)l, 16, 0, 0);
}

// ---------------- small utility kernels ----------------

__global__ void zero_int_kernel(int* p, int n) {
    int i = blockIdx.x * 256 + threadIdx.x;
    if (i < n) p[i] = 0;
}

// v[l][d][h] = sum_c We[l][d][h*32+c]*att_edge[l][h][c]
__global__ void precompute_kernel(const float* __restrict__ We,
                                  const float* __restrict__ att_e,
                                  float* __restrict__ v) {
    int t = threadIdx.x;  // 1024 threads
    int l = t >> 8, rem = t & 255, d = rem >> 3, hh = rem & 7;
    float s = 0.f;
#pragma unroll
    for (int c = 0; c < 32; ++c)
        s += We[((size_t)(l * 32 + d)) * 256 + hh * 32 + c] * att_e[l * 256 + hh * 32 + c];
    v[t] = s;  // v[l*256 + d*8 + h]
}

// column partial sums of edge_attr: part[1024][32] (deterministic)
__global__ __launch_bounds__(256) void col_partial(const float* __restrict__ ea,
                                                   float* __restrict__ part) {
    int t = threadIdx.x;
    int c = t & 7;   // float4 col group
    int rg = t >> 3; // 0..31 row group
    float4 acc = {0.f, 0.f, 0.f, 0.f};
    for (int r = blockIdx.x * 32 + rg; r < EE; r += 1024 * 32) {
        float4 f = *(const float4*)&ea[(size_t)r * 32 + c * 4];
        acc.x += f.x; acc.y += f.y; acc.z += f.z; acc.w += f.w;
    }
    __shared__ float4 sm[256];
    sm[t] = acc;
    __syncthreads();
    for (int s = 16; s > 0; s >>= 1) {
        if (rg < s) {
            float4 o = sm[(rg + s) * 8 + c];
            float4 m = sm[t];
            m.x += o.x; m.y += o.y; m.z += o.z; m.w += o.w;
            sm[t] = m;
        }
        __syncthreads();
    }
    if (t < 8) *(float4*)&part[(size_t)blockIdx.x * 32 + t * 4] = sm[t];
}

// reduce part[1024][32] -> mean_ea[32] (deterministic, 4-way ILP)
__global__ __launch_bounds__(256) void col_final(const float* __restrict__ part,
                                                 float* __restrict__ mean_ea) {
    int t = threadIdx.x;
    int v = t & 31, c = t >> 5;  // 8 chunks
    float a0 = 0.f, a1 = 0.f, a2 = 0.f, a3 = 0.f;
    for (int b = c; b < 1024; b += 32) {
        a0 += part[(size_t)(b) * 32 + v];
        a1 += part[(size_t)(b + 8) * 32 + v];
        a2 += part[(size_t)(b + 16) * 32 + v];
        a3 += part[(size_t)(b + 24) * 32 + v];
    }
    float s = (a0 + a1) + (a2 + a3);
    __shared__ float sm[256];
    sm[t] = s;
    __syncthreads();
    if (c == 0) {
        float tot = 0.f;
#pragma unroll
        for (int k = 0; k < 8; ++k) tot += sm[k * 32 + v];
        mean_ea[v] = tot * (1.0f / EE);
    }
}

__global__ void hist_kernel(const int* __restrict__ ei, int* __restrict__ cnt) {
    int i = blockIdx.x * 256 + threadIdx.x;
    if (i >= ETOT) return;
    int dst = (i < EE) ? ei[EE + i] : (i - EE);
    atomicAdd(&cnt[dst], 1);
}

// 3-phase scan over cnt[NN] -> row_ptr/fill (1024 elems per block)
__global__ __launch_bounds__(256) void scan_phase1(const int* __restrict__ cnt,
                                                   int* __restrict__ bsum) {
    int b = blockIdx.x, t = threadIdx.x;
    int i0 = b * 1024 + t * 4;
    int s = 0;
#pragma unroll
    for (int r = 0; r < 4; ++r) s += (i0 + r < NN) ? cnt[i0 + r] : 0;
    for (int off = 1; off < 64; off <<= 1) s += __shfl_xor(s, off);
    __shared__ int wtot[4];
    if ((t & 63) == 0) wtot[t >> 6] = s;
    __syncthreads();
    if (t == 0) bsum[b] = wtot[0] + wtot[1] + wtot[2] + wtot[3];
}

__global__ void scan_phase2(int* __restrict__ bsum, int* __restrict__ row_ptr, int nb) {
    int lane = threadIdx.x;  // 64 threads
    int vv = (lane < nb) ? bsum[lane] : 0;
    int incl = vv;
    for (int off = 1; off < 64; off <<= 1) {
        int u = __shfl_up(incl, off);
        if (lane >= off) incl += u;
    }
    if (lane < nb) bsum[lane] = incl - vv;
    if (lane == 0) row_ptr[NN] = ETOT;
}

__global__ __launch_bounds__(256) void scan_phase3(const int* __restrict__ cnt,
                                                   const int* __restrict__ bsum,
                                                   int* __restrict__ row_ptr,
                                                   int* __restrict__ fill) {
    int b = blockIdx.x, t = threadIdx.x;
    int i0 = b * 1024 + t * 4;
    int v[4];
    int s = 0;
#pragma unroll
    for (int r = 0; r < 4; ++r) { v[r] = (i0 + r < NN) ? cnt[i0 + r] : 0; s += v[r]; }
    int lane = t & 63, wv = t >> 6;
    int incl = s;
    for (int off = 1; off < 64; off <<= 1) {
        int u = __shfl_up(incl, off);
        if (lane >= off) incl += u;
    }
    __shared__ int wtot[4];
    if (lane == 63) wtot[wv] = incl;
    __syncthreads();
    int wpref = 0;
    for (int k = 0; k < wv; ++k) wpref += wtot[k];
    int start = bsum[b] + wpref + incl - s;
#pragma unroll
    for (int r = 0; r < 4; ++r) {
        int i = i0 + r;
        if (i < NN) { row_ptr[i] = start; fill[i] = start; }
        start += v[r];
    }
}

__global__ void scatter_kernel(const int* __restrict__ ei, int* __restrict__ fill,
                               int* __restrict__ sorted_src, int* __restrict__ sorted_eid) {
    int i = blockIdx.x * 256 + threadIdx.x;
    if (i >= ETOT) return;
    int dst, src;
    if (i < EE) { src = ei[i]; dst = ei[EE + i]; }
    else        { src = i - EE; dst = i - EE; }
    int pos = atomicAdd(&fill[dst], 1);
    sorted_src[pos] = src;
    sorted_eid[pos] = i;
}

// split weights into transposed [n][k] bf16 hi/lo panels
__global__ __launch_bounds__(256) void split_weights(const float* __restrict__ w_in,
                                                     const float* __restrict__ W_l,
                                                     ushort* __restrict__ bh,
                                                     ushort* __restrict__ bl) {
    int t = blockIdx.x * 256 + threadIdx.x;
    if (t >= 32768 + 4 * 65536) return;
    float val;
    size_t dst;
    if (t < 32768) {
        int n = t >> 7, k = t & 127;
        val = w_in[(size_t)k * 256 + n];
        dst = (size_t)n * 128 + k;
    } else {
        int u = t - 32768;
        int l = u >> 16, r = u & 65535;
        int n = r >> 8, k = r & 255;
        val = W_l[(size_t)l * 65536 + (size_t)k * 256 + n];
        dst = 32768 + (size_t)l * 65536 + (size_t)n * 256 + k;
    }
    ushort hi = f2bf_rn(val);
    bh[dst] = hi;
    bl[dst] = f2bf_rn(val - bf2f(hi));
}

// pre-split x into bf16 hi(trunc)/lo(RN), zero-padded to MPAD rows
__global__ void split_x(const float* __restrict__ x, ushort* __restrict__ xh,
                        ushort* __restrict__ xl) {
    int i = blockIdx.x * 256 + threadIdx.x;
    if (i >= MPAD * 128) return;
    int n = i >> 7;
    float val = (n < NN) ? x[i] : 0.f;
    union { float f; uint u; } uv; uv.f = val;
    ushort hi = (ushort)(uv.u >> 16);
    xh[i] = hi;
    xl[i] = f2bf_rn(val - bf2f(hi));
}

// all-layer edge logits in SORTED-POS order: gather edge_attr row (one full
// 128B line) or mean_ea for self-loops, write all 4 layer planes coalesced.
__global__ __launch_bounds__(256) void edge_logits(const float* __restrict__ edge_attr,
                                                   const float* __restrict__ mean_ea,
                                                   const int* __restrict__ sorted_eid,
                                                   const float* __restrict__ v,
                                                   _Float16* __restrict__ e_all) {
    __shared__ float vs[1024];
    for (int t = threadIdx.x; t < 1024; t += 256) vs[t] = v[t];
    __syncthreads();
    int p = blockIdx.x * 256 + threadIdx.x;
    if (p >= ETOT) return;
    int eid = sorted_eid[p];
    const float4* row = (const float4*)((eid < EE) ? (edge_attr + (size_t)eid * 32) : mean_ea);
    float r[32];
#pragma unroll
    for (int q = 0; q < 8; ++q) {
        float4 f = row[q];
        r[q * 4] = f.x; r[q * 4 + 1] = f.y; r[q * 4 + 2] = f.z; r[q * 4 + 3] = f.w;
    }
    float acc[4][8] = {};
#pragma unroll 4
    for (int d = 0; d < 32; ++d) {
        float rv = r[d];
#pragma unroll
        for (int l = 0; l < 4; ++l)
#pragma unroll
            for (int h = 0; h < 8; ++h) acc[l][h] += rv * vs[l * 256 + d * 8 + h];
    }
#pragma unroll
    for (int l = 0; l < 4; ++l) {
        union { uint4 u; _Float16 h[8]; } pk;
#pragma unroll
        for (int h = 0; h < 8; ++h) pk.h[h] = (_Float16)acc[l][h];
        *(uint4*)&e_all[(size_t)l * ETOT * 8 + (size_t)p * 8] = pk.u;
    }
}

// ---------------- MFMA GEMM (BK=64, 48KB LDS -> 3 blocks/CU) ----------------
// A pre-split bf16 hi/lo [row][K]; B pre-split transposed [n][K] hi/lo.
// 3-term: Ah*Bh + Ah*Bl + Al*Bh. Ah/Bh/Bl staged via global_load_lds
// (pre-swizzled source); Al loaded DIRECTLY to registers per fragment
// (one use, no cross-wave reuse -> LDS staging was pure overhead).
// MODE 0: out = h pair (bf16 hi/lo) + bias.
// MODE 1: out = hp fp16, no bias; FUSED a_s/a_d epilogue from the f32 acc.
template <int MODE>
__global__ __launch_bounds__(256) void gemm_mfma(const ushort* __restrict__ Ah,
                                                 const ushort* __restrict__ Al,
                                                 const ushort* __restrict__ Bh,
                                                 const ushort* __restrict__ Bl,
                                                 const float* __restrict__ bias,
                                                 _Float16* __restrict__ hp_out,
                                                 ushort* __restrict__ hh_out,
                                                 ushort* __restrict__ hl_out,
                                                 const float* __restrict__ att_s,
                                                 const float* __restrict__ att_d,
                                                 float* __restrict__ as_out,
                                                 float* __restrict__ ad_out,
                                                 int M, int K) {
    __shared__ __align__(16) ushort sAh[8192], sBh[8192], sBl[8192];
    int tid = threadIdx.x;
    int m0 = blockIdx.x * 128, n0 = blockIdx.y * 128;
    int wid = tid >> 6, lane = tid & 63;
    int wm = wid & 1, wn = wid >> 1;
    int lr = lane & 15, grp = lane >> 4;
    f32x4 acc[4][4];
#pragma unroll
    for (int i = 0; i < 4; ++i)
#pragma unroll
        for (int j = 0; j < 4; ++j) acc[i][j] = (f32x4){0.f, 0.f, 0.f, 0.f};

    for (int k0 = 0; k0 < K; k0 += 64) {
        if (k0) __syncthreads();
#pragma unroll
        for (int i = 0; i < 4; ++i) {
            int ldso = wid * 2048 + i * 512;           // ushort units, wave-uniform
            int o = ldso + lane * 8;
            int m = o >> 6;                             // local row (64 ushorts/row)
            int kl = ((((o >> 3) & 7) ^ (m & 7)) << 3) + k0;
            size_t ga = (size_t)(m0 + m) * K + kl;
            size_t gb = (size_t)(n0 + m) * K + kl;
            g2l16(Ah + ga, sAh + ldso);
            g2l16(Bh + gb, sBh + ldso);
            g2l16(Bl + gb, sBl + ldso);
        }
        __syncthreads();
#pragma unroll
        for (int ks = 0; ks < 2; ++ks) {
            bf16x8 vbh[4], vbl[4];
#pragma unroll
            for (int j = 0; j < 4; ++j) {
                int n = wn * 64 + j * 16 + lr;
                int off = n * 64 + ((ks * 32 + grp * 8) ^ ((n & 7) << 3));
                vbh[j] = *(const bf16x8*)&sBh[off];
                vbl[j] = *(const bf16x8*)&sBl[off];
            }
#pragma unroll
            for (int i = 0; i < 4; ++i) {
                int mm = wm * 64 + i * 16 + lr;
                int off = mm * 64 + ((ks * 32 + grp * 8) ^ ((mm & 7) << 3));
                bf16x8 vah = *(const bf16x8*)&sAh[off];
                // Al fragment direct from global (64B-contiguous per row)
                bf16x8 valo = *(const bf16x8*)(Al + (size_t)(m0 + mm) * K + k0 + ks * 32 + grp * 8);
#pragma unroll
                for (int j = 0; j < 4; ++j) {
                    acc[i][j] = __builtin_amdgcn_mfma_f32_16x16x32_bf16(valo, vbh[j], acc[i][j], 0, 0, 0);
                    acc[i][j] = __builtin_amdgcn_mfma_f32_16x16x32_bf16(vah, vbl[j], acc[i][j], 0, 0, 0);
                    acc[i][j] = __builtin_amdgcn_mfma_f32_16x16x32_bf16(vah, vbh[j], acc[i][j], 0, 0, 0);
                }
            }
        }
    }
    // epilogue: C/D layout col=lane&15, row=(lane>>4)*4+reg [m89-verified]
#pragma unroll
    for (int j = 0; j < 4; ++j) {
        int c = n0 + wn * 64 + j * 16 + lr;
        float bj = (MODE == 0) ? bias[c] : 0.f;
#pragma unroll
        for (int i = 0; i < 4; ++i) {
            int mb = m0 + wm * 64 + i * 16 + grp * 4;
#pragma unroll
            for (int r = 0; r < 4; ++r) {
                int row = mb + r;
                if (row < M) {
                    float val = acc[i][j][r] + bj;
                    if (MODE == 0) {
                        union { float f; uint u; } uv; uv.f = val;
                        ushort hi = (ushort)(uv.u >> 16);
                        hh_out[(size_t)row * 256 + c] = hi;
                        hl_out[(size_t)row * 256 + c] = f2bf_rn(val - bf2f(hi));
                    } else {
                        hp_out[(size_t)row * 256 + c] = (_Float16)val;
                    }
                }
            }
        }
    }
    if (MODE == 1) {
        // fused a_s/a_d from f32 accumulators
        int h0 = (n0 >> 5) + wn * 2;   // first of this wave's two heads
        float as_w[4], ad_w[4];
#pragma unroll
        for (int j = 0; j < 4; ++j) {
            int h = h0 + (j >> 1);
            int cw = ((j & 1) << 4) + lr;
            as_w[j] = att_s[h * 32 + cw];
            ad_w[j] = att_d[h * 32 + cw];
        }
#pragma unroll
        for (int i = 0; i < 4; ++i) {
#pragma unroll
            for (int r = 0; r < 4; ++r) {
                float ps0 = acc[i][0][r] * as_w[0] + acc[i][1][r] * as_w[1];
                float ps1 = acc[i][2][r] * as_w[2] + acc[i][3][r] * as_w[3];
                float pd0 = acc[i][0][r] * ad_w[0] + acc[i][1][r] * ad_w[1];
                float pd1 = acc[i][2][r] * ad_w[2] + acc[i][3][r] * ad_w[3];
#pragma unroll
                for (int off = 1; off < 16; off <<= 1) {
                    ps0 += __shfl_xor(ps0, off);
                    ps1 += __shfl_xor(ps1, off);
                    pd0 += __shfl_xor(pd0, off);
                    pd1 += __shfl_xor(pd1, off);
                }
                if (lr == 0) {
                    int row = m0 + wm * 64 + i * 16 + grp * 4 + r;
                    if (row < M) {
                        as_out[row * 8 + h0]     = ps0;
                        as_out[row * 8 + h0 + 1] = ps1;
                        ad_out[row * 8 + h0]     = pd0;
                        ad_out[row * 8 + h0 + 1] = pd1;
                    }
                }
            }
        }
    }
}

// ---------------- aggregate ----------------

// one wave per dst node; pipelined e-phase + 16B/lane gather accumulation.
// LAST=1: fuse output projection (dot with w_out + wave reduce) -> out[n],
// skipping the h_hi/h_lo writes entirely.
template <int LAST>
__global__ __launch_bounds__(256) void aggregate_kernel(const _Float16* __restrict__ hp,
                                                        const float* __restrict__ a_s,
                                                        const float* __restrict__ a_d,
                                                        const _Float16* __restrict__ e_l,
                                                        const int* __restrict__ sorted_src,
                                                        const int* __restrict__ row_ptr,
                                                        const float* __restrict__ bias,
                                                        ushort* __restrict__ h_hi,
                                                        ushort* __restrict__ h_lo,
                                                        const float* __restrict__ w_out,
                                                        const float* __restrict__ b_out,
                                                        float* __restrict__ out) {
    int n = (blockIdx.x * 256 + threadIdx.x) >> 6;
    if (n >= NN) return;
    int lane = threadIdx.x & 63;
    int h1 = lane & 7;        // e-phase head
    int eslot = lane >> 3;    // e-phase edge slot
    int chan = lane & 31;     // accum: channels chan*8..chan*8+7 (16B fp16)
    int half = lane >> 5;     // accum: 0 -> even slots, 1 -> odd slots
    int hh = chan >> 2;       // head of owned channels
    int beg = row_ptr[n], end = row_ptr[n + 1];   // deg >= 1 (self-loop)
    float ad1 = a_d[n * 8 + h1];
    float s = 0.f;
    float acc[8] = {};

    // prologue: load batch 0 inputs
    int j0 = beg + eslot;
    bool valid = j0 < end;
    int jc = valid ? j0 : (end - 1);
    int srce = sorted_src[jc];
    float asv = a_s[srce * 8 + h1];
    float elv = (float)e_l[(size_t)jc * 8 + h1];

    for (int base = beg; base < end; base += 8) {
        // prefetch next batch (overlaps with current batch's gather+FMA)
        int srce_n = 0; float asn = 0.f, eln = 0.f; bool nvalid = false;
        int nbase = base + 8;
        if (nbase < end) {
            int nj = nbase + eslot;
            nvalid = nj < end;
            int njc = nvalid ? nj : (end - 1);
            srce_n = sorted_src[njc];
            asn = a_s[srce_n * 8 + h1];
            eln = (float)e_l[(size_t)njc * 8 + h1];
        }
        // current batch weight
        float e = asv + ad1 + elv;
        e = (e >= 0.f) ? e : NEG_SLOPE * e;
        float w1 = valid ? __expf(e) : 0.f;
        // each half processes 4 of the 8 slots: slot = p*2 + half
        float wv[4];
        int sv[4];
#pragma unroll
        for (int p = 0; p < 4; ++p) {
            int slot = p * 2 + half;
            wv[p] = __shfl(w1, slot * 8 + hh);
            sv[p] = __shfl(srce, slot * 8);
        }
        union { uint4 u; _Float16 q[8]; } hv[4];
#pragma unroll
        for (int p = 0; p < 4; ++p)
            hv[p].u = *(const uint4*)&hp[(size_t)sv[p] * 256 + chan * 8];
#pragma unroll
        for (int p = 0; p < 4; ++p) {
            float w = wv[p];
            s += w;
#pragma unroll
            for (int k = 0; k < 8; ++k) acc[k] += w * (float)hv[p].q[k];
        }
        // rotate pipeline
        srce = srce_n; asv = asn; elv = eln; valid = nvalid;
    }
    // merge the two halves (lane ^ 32 owns same channels, other slot parity)
    s += __shfl_xor(s, 32);
#pragma unroll
    for (int k = 0; k < 8; ++k) acc[k] += __shfl_xor(acc[k], 32);

    float inv = 1.0f / (s + 1e-16f);
    const float4* b4 = (const float4*)&bias[chan * 8];
    float4 bA = b4[0], bB = b4[1];
    float o[8];
    o[0] = acc[0] * inv + bA.x; o[1] = acc[1] * inv + bA.y;
    o[2] = acc[2] * inv + bA.z; o[3] = acc[3] * inv + bA.w;
    o[4] = acc[4] * inv + bB.x; o[5] = acc[5] * inv + bB.y;
    o[6] = acc[6] * inv + bB.z; o[7] = acc[7] * inv + bB.w;
    if (LAST) {
        // fused output projection: both halves hold the full row; reduce 32 lanes
        const float4* w4 = (const float4*)&w_out[chan * 8];
        float4 wA = w4[0], wB = w4[1];
        float dot = o[0] * wA.x + o[1] * wA.y + o[2] * wA.z + o[3] * wA.w +
                    o[4] * wB.x + o[5] * wB.y + o[6] * wB.z + o[7] * wB.w;
        for (int off = 1; off < 32; off <<= 1) dot += __shfl_xor(dot, off);
        if (lane == 0) out[n] = dot + b_out[0];
        return;
    }
    union { uint4 u; ushort v[8]; } pk;
    if (half == 0) {
#pragma unroll
        for (int k = 0; k < 8; ++k) {
            union { float f; uint u; } uv; uv.f = o[k];
            pk.v[k] = (ushort)(uv.u >> 16);
        }
        *(uint4*)&h_hi[(size_t)n * 256 + chan * 8] = pk.u;
    } else {
#pragma unroll
        for (int k = 0; k < 8; ++k) {
            union { float f; uint u; } uv; uv.f = o[k];
            ushort hi = (ushort)(uv.u >> 16);
            pk.v[k] = f2bf_rn(o[k] - bf2f(hi));
        }
        *(uint4*)&h_lo[(size_t)n * 256 + chan * 8] = pk.u;
    }
}

// ---------------- launch ----------------

extern "C" void kernel_launch(void* const* d_in, const int* in_sizes, int n_in,
                              void* d_out, int out_size, void* d_ws, size_t ws_size,
                              hipStream_t stream) {
    const float* x         = (const float*)d_in[0];
    const int*   edge_idx  = (const int*)d_in[1];
    const float* edge_attr = (const float*)d_in[2];
    const float* w_in      = (const float*)d_in[3];
    const float* b_in      = (const float*)d_in[4];
    const float* W_l       = (const float*)d_in[5];
    const float* We_l      = (const float*)d_in[6];
    const float* att_src   = (const float*)d_in[7];
    const float* att_dst   = (const float*)d_in[8];
    const float* att_edge  = (const float*)d_in[9];
    const float* bias_l    = (const float*)d_in[10];
    const float* w_out     = (const float*)d_in[11];
    const float* b_out     = (const float*)d_in[12];
    float* out = (float*)d_out;

    char* ws = (char*)d_ws;
    size_t off = 0;
    auto alloc = [&](size_t bytes) -> void* {
        void* p = ws + off;
        off = (off + bytes + 255) & ~(size_t)255;
        return p;
    };
    ushort*   h_hi       = (ushort*)alloc((size_t)MPAD * 256 * 2);
    ushort*   h_lo       = (ushort*)alloc((size_t)MPAD * 256 * 2);
    _Float16* hp16       = (_Float16*)alloc((size_t)MPAD * 256 * 2);
    float*    a_s        = (float*)alloc((size_t)NN * 8 * 4);
    float*    a_d        = (float*)alloc((size_t)NN * 8 * 4);
    int*      sorted_src = (int*)alloc((size_t)ETOT * 4);
    int*      sorted_eid = (int*)alloc((size_t)ETOT * 4);
    int*      row_ptr    = (int*)alloc((size_t)(NN + 1) * 4);
    int*      fill       = (int*)alloc((size_t)NN * 4);
    int*      cnt        = (int*)alloc((size_t)NN * 4);
    int*      bsum       = (int*)alloc(64 * 4);
    float*    col_part   = (float*)alloc((size_t)1024 * 32 * 4);
    float*    mean_ea    = (float*)alloc(32 * 4);
    float*    v          = (float*)alloc(1024 * 4);
    ushort*   bsp_hi     = (ushort*)alloc((size_t)294912 * 2);
    ushort*   bsp_lo     = (ushort*)alloc((size_t)294912 * 2);
    // union region: {xh, xl} then (after input GEMM) e_all overlays it
    char*     uni        = (char*)alloc((size_t)4 * ETOT * 8 * 2);  // 54.4 MB
    ushort*   xh         = (ushort*)uni;
    ushort*   xl         = (ushort*)(uni + (size_t)MPAD * 128 * 2);
    _Float16* e_all      = (_Float16*)uni;

    const int NB = (NN + 1023) / 1024;  // 49

    // weight prep + input projection (uses xh/xl before e_all overlays)
    zero_int_kernel<<<(NN + 255) / 256, 256, 0, stream>>>(cnt, NN);
    precompute_kernel<<<1, 1024, 0, stream>>>(We_l, att_edge, v);
    col_partial<<<1024, 256, 0, stream>>>(edge_attr, col_part);
    col_final<<<1, 256, 0, stream>>>(col_part, mean_ea);
    split_weights<<<(294912 + 255) / 256, 256, 0, stream>>>(w_in, W_l, bsp_hi, bsp_lo);
    split_x<<<(MPAD * 128 + 255) / 256, 256, 0, stream>>>(x, xh, xl);

    dim3 ggrid((NN + 127) / 128, 2);
    gemm_mfma<0><<<ggrid, 256, 0, stream>>>(xh, xl, bsp_hi, bsp_lo, b_in,
                                            nullptr, h_hi, h_lo,
                                            nullptr, nullptr, nullptr, nullptr,
                                            NN, IN_DIM);

    // graph build + all-layer edge logits (e_all overlays xh/xl — input GEMM done)
    hist_kernel<<<(ETOT + 255) / 256, 256, 0, stream>>>(edge_idx, cnt);
    scan_phase1<<<NB, 256, 0, stream>>>(cnt, bsum);
    scan_phase2<<<1, 64, 0, stream>>>(bsum, row_ptr, NB);
    scan_phase3<<<NB, 256, 0, stream>>>(cnt, bsum, row_ptr, fill);
    scatter_kernel<<<(ETOT + 255) / 256, 256, 0, stream>>>(edge_idx, fill, sorted_src, sorted_eid);
    edge_logits<<<(ETOT + 255) / 256, 256, 0, stream>>>(edge_attr, mean_ea, sorted_eid, v, e_all);

    for (int l = 0; l < LL; ++l) {
        const ushort* wh = bsp_hi + 32768 + (size_t)l * 65536;
        const ushort* wl = bsp_lo + 32768 + (size_t)l * 65536;
        gemm_mfma<1><<<ggrid, 256, 0, stream>>>(h_hi, h_lo, wh, wl, nullptr,
                                                hp16, nullptr, nullptr,
                                                att_src + l * 256, att_dst + l * 256,
                                                a_s, a_d, NN, EMB);
        if (l < LL - 1) {
            aggregate_kernel<0><<<NN / 4, 256, 0, stream>>>(
                hp16, a_s, a_d, e_all + (size_t)l * ETOT * 8, sorted_src, row_ptr,
                bias_l + l * 256, h_hi, h_lo, nullptr, nullptr, nullptr);
        } else {
            aggregate_kernel<1><<<NN / 4, 256, 0, stream>>>(
                hp16, a_s, a_d, e_all + (size_t)l * ETOT * 8, sorted_src, row_ptr,
                bias_l + l * 256, nullptr, nullptr, w_out, b_out, out);
        }
    }
}

// Round 14
// 668.010 us; speedup vs baseline: 1.0473x; 1.0473x over previous
//
#include <hip/hip_runtime.h>

#define NN 50000
#define MPAD 50048
#define EE 800000
#define ETOT (EE + NN)
#define IN_DIM 128
#define EDGE_DIM 32
#define EMB 256
#define HH 8
#define LL 4
#define NEG_SLOPE 0.2f

typedef __attribute__((ext_vector_type(8))) short bf16x8;
typedef __attribute__((ext_vector_type(4))) float f32x4;

__device__ inline ushort f2bf_rn(float x) {
    union { float f; uint u; } v; v.f = x;
    uint r = v.u + 0x7FFFu + ((v.u >> 16) & 1u);
    return (ushort)(r >> 16);
}
__device__ inline float bf2f(ushort b) {
    union { uint u; float f; } v; v.u = ((uint)b) << 16;
    return v.f;
}

__device__ __forceinline__ void g2l16(const void* g, void* l) {
    __builtin_amdgcn_global_load_lds((const __attribute__((address_space(1))) void*)g,
                                     (__attribute__((address_space(3))) void*)l, 16, 0, 0);
}

// ---------------- small utility kernels ----------------

__global__ void zero_int_kernel(int* p, int n) {
    int i = blockIdx.x * 256 + threadIdx.x;
    if (i < n) p[i] = 0;
}

// v[l][d][h] = sum_c We[l][d][h*32+c]*att_edge[l][h][c]
__global__ void precompute_kernel(const float* __restrict__ We,
                                  const float* __restrict__ att_e,
                                  float* __restrict__ v) {
    int t = threadIdx.x;  // 1024 threads
    int l = t >> 8, rem = t & 255, d = rem >> 3, hh = rem & 7;
    float s = 0.f;
#pragma unroll
    for (int c = 0; c < 32; ++c)
        s += We[((size_t)(l * 32 + d)) * 256 + hh * 32 + c] * att_e[l * 256 + hh * 32 + c];
    v[t] = s;  // v[l*256 + d*8 + h]
}

// column partial sums of edge_attr: part[1024][32] (deterministic)
__global__ __launch_bounds__(256) void col_partial(const float* __restrict__ ea,
                                                   float* __restrict__ part) {
    int t = threadIdx.x;
    int c = t & 7;   // float4 col group
    int rg = t >> 3; // 0..31 row group
    float4 acc = {0.f, 0.f, 0.f, 0.f};
    for (int r = blockIdx.x * 32 + rg; r < EE; r += 1024 * 32) {
        float4 f = *(const float4*)&ea[(size_t)r * 32 + c * 4];
        acc.x += f.x; acc.y += f.y; acc.z += f.z; acc.w += f.w;
    }
    __shared__ float4 sm[256];
    sm[t] = acc;
    __syncthreads();
    for (int s = 16; s > 0; s >>= 1) {
        if (rg < s) {
            float4 o = sm[(rg + s) * 8 + c];
            float4 m = sm[t];
            m.x += o.x; m.y += o.y; m.z += o.z; m.w += o.w;
            sm[t] = m;
        }
        __syncthreads();
    }
    if (t < 8) *(float4*)&part[(size_t)blockIdx.x * 32 + t * 4] = sm[t];
}

// reduce part[1024][32] -> mean_ea[32] (deterministic, 4-way ILP)
__global__ __launch_bounds__(256) void col_final(const float* __restrict__ part,
                                                 float* __restrict__ mean_ea) {
    int t = threadIdx.x;
    int v = t & 31, c = t >> 5;  // 8 chunks
    float a0 = 0.f, a1 = 0.f, a2 = 0.f, a3 = 0.f;
    for (int b = c; b < 1024; b += 32) {
        a0 += part[(size_t)(b) * 32 + v];
        a1 += part[(size_t)(b + 8) * 32 + v];
        a2 += part[(size_t)(b + 16) * 32 + v];
        a3 += part[(size_t)(b + 24) * 32 + v];
    }
    float s = (a0 + a1) + (a2 + a3);
    __shared__ float sm[256];
    sm[t] = s;
    __syncthreads();
    if (c == 0) {
        float tot = 0.f;
#pragma unroll
        for (int k = 0; k < 8; ++k) tot += sm[k * 32 + v];
        mean_ea[v] = tot * (1.0f / EE);
    }
}

__global__ void hist_kernel(const int* __restrict__ ei, int* __restrict__ cnt) {
    int i = blockIdx.x * 256 + threadIdx.x;
    if (i >= ETOT) return;
    int dst = (i < EE) ? ei[EE + i] : (i - EE);
    atomicAdd(&cnt[dst], 1);
}

// 3-phase scan over cnt[NN] -> row_ptr/fill (1024 elems per block)
__global__ __launch_bounds__(256) void scan_phase1(const int* __restrict__ cnt,
                                                   int* __restrict__ bsum) {
    int b = blockIdx.x, t = threadIdx.x;
    int i0 = b * 1024 + t * 4;
    int s = 0;
#pragma unroll
    for (int r = 0; r < 4; ++r) s += (i0 + r < NN) ? cnt[i0 + r] : 0;
    for (int off = 1; off < 64; off <<= 1) s += __shfl_xor(s, off);
    __shared__ int wtot[4];
    if ((t & 63) == 0) wtot[t >> 6] = s;
    __syncthreads();
    if (t == 0) bsum[b] = wtot[0] + wtot[1] + wtot[2] + wtot[3];
}

__global__ void scan_phase2(int* __restrict__ bsum, int* __restrict__ row_ptr, int nb) {
    int lane = threadIdx.x;  // 64 threads
    int vv = (lane < nb) ? bsum[lane] : 0;
    int incl = vv;
    for (int off = 1; off < 64; off <<= 1) {
        int u = __shfl_up(incl, off);
        if (lane >= off) incl += u;
    }
    if (lane < nb) bsum[lane] = incl - vv;
    if (lane == 0) row_ptr[NN] = ETOT;
}

__global__ __launch_bounds__(256) void scan_phase3(const int* __restrict__ cnt,
                                                   const int* __restrict__ bsum,
                                                   int* __restrict__ row_ptr,
                                                   int* __restrict__ fill) {
    int b = blockIdx.x, t = threadIdx.x;
    int i0 = b * 1024 + t * 4;
    int v[4];
    int s = 0;
#pragma unroll
    for (int r = 0; r < 4; ++r) { v[r] = (i0 + r < NN) ? cnt[i0 + r] : 0; s += v[r]; }
    int lane = t & 63, wv = t >> 6;
    int incl = s;
    for (int off = 1; off < 64; off <<= 1) {
        int u = __shfl_up(incl, off);
        if (lane >= off) incl += u;
    }
    __shared__ int wtot[4];
    if (lane == 63) wtot[wv] = incl;
    __syncthreads();
    int wpref = 0;
    for (int k = 0; k < wv; ++k) wpref += wtot[k];
    int start = bsum[b] + wpref + incl - s;
#pragma unroll
    for (int r = 0; r < 4; ++r) {
        int i = i0 + r;
        if (i < NN) { row_ptr[i] = start; fill[i] = start; }
        start += v[r];
    }
}

__global__ void scatter_kernel(const int* __restrict__ ei, int* __restrict__ fill,
                               int* __restrict__ sorted_src, int* __restrict__ sorted_eid) {
    int i = blockIdx.x * 256 + threadIdx.x;
    if (i >= ETOT) return;
    int dst, src;
    if (i < EE) { src = ei[i]; dst = ei[EE + i]; }
    else        { src = i - EE; dst = i - EE; }
    int pos = atomicAdd(&fill[dst], 1);
    sorted_src[pos] = src;
    sorted_eid[pos] = i;
}

// split weights into transposed [n][k] bf16 hi/lo panels
__global__ __launch_bounds__(256) void split_weights(const float* __restrict__ w_in,
                                                     const float* __restrict__ W_l,
                                                     ushort* __restrict__ bh,
                                                     ushort* __restrict__ bl) {
    int t = blockIdx.x * 256 + threadIdx.x;
    if (t >= 32768 + 4 * 65536) return;
    float val;
    size_t dst;
    if (t < 32768) {
        int n = t >> 7, k = t & 127;
        val = w_in[(size_t)k * 256 + n];
        dst = (size_t)n * 128 + k;
    } else {
        int u = t - 32768;
        int l = u >> 16, r = u & 65535;
        int n = r >> 8, k = r & 255;
        val = W_l[(size_t)l * 65536 + (size_t)k * 256 + n];
        dst = 32768 + (size_t)l * 65536 + (size_t)n * 256 + k;
    }
    ushort hi = f2bf_rn(val);
    bh[dst] = hi;
    bl[dst] = f2bf_rn(val - bf2f(hi));
}

// pre-split x into bf16 hi(trunc)/lo(RN), zero-padded to MPAD rows
__global__ void split_x(const float* __restrict__ x, ushort* __restrict__ xh,
                        ushort* __restrict__ xl) {
    int i = blockIdx.x * 256 + threadIdx.x;
    if (i >= MPAD * 128) return;
    int n = i >> 7;
    float val = (n < NN) ? x[i] : 0.f;
    union { float f; uint u; } uv; uv.f = val;
    ushort hi = (ushort)(uv.u >> 16);
    xh[i] = hi;
    xl[i] = f2bf_rn(val - bf2f(hi));
}

// all-layer edge logits in SORTED-POS order: gather edge_attr row (one full
// 128B line) or mean_ea for self-loops, write all 4 layer planes coalesced.
__global__ __launch_bounds__(256) void edge_logits(const float* __restrict__ edge_attr,
                                                   const float* __restrict__ mean_ea,
                                                   const int* __restrict__ sorted_eid,
                                                   const float* __restrict__ v,
                                                   _Float16* __restrict__ e_all) {
    __shared__ float vs[1024];
    for (int t = threadIdx.x; t < 1024; t += 256) vs[t] = v[t];
    __syncthreads();
    int p = blockIdx.x * 256 + threadIdx.x;
    if (p >= ETOT) return;
    int eid = sorted_eid[p];
    const float4* row = (const float4*)((eid < EE) ? (edge_attr + (size_t)eid * 32) : mean_ea);
    float r[32];
#pragma unroll
    for (int q = 0; q < 8; ++q) {
        float4 f = row[q];
        r[q * 4] = f.x; r[q * 4 + 1] = f.y; r[q * 4 + 2] = f.z; r[q * 4 + 3] = f.w;
    }
    float acc[4][8] = {};
#pragma unroll 4
    for (int d = 0; d < 32; ++d) {
        float rv = r[d];
#pragma unroll
        for (int l = 0; l < 4; ++l)
#pragma unroll
            for (int h = 0; h < 8; ++h) acc[l][h] += rv * vs[l * 256 + d * 8 + h];
    }
#pragma unroll
    for (int l = 0; l < 4; ++l) {
        union { uint4 u; _Float16 h[8]; } pk;
#pragma unroll
        for (int h = 0; h < 8; ++h) pk.h[h] = (_Float16)acc[l][h];
        *(uint4*)&e_all[(size_t)l * ETOT * 8 + (size_t)p * 8] = pk.u;
    }
}

// ---------------- MFMA GEMM (BK=64, 64KB LDS — r12 verified config) ----------------
// A pre-split bf16 hi/lo [row][K]; B pre-split transposed [n][K] hi/lo.
// 3-term: Ah*Bh + Ah*Bl + Al*Bh. All four images staged via global_load_lds
// with pre-swizzled source (coalesced); r13 showed direct per-fragment global
// loads of Al are a 512B-strided gather inside the MFMA stream -> regression.
// MODE 0: out = h pair (bf16 hi/lo) + bias.
// MODE 1: out = hp fp16, no bias; FUSED a_s/a_d epilogue from the f32 acc.
template <int MODE>
__global__ __launch_bounds__(256) void gemm_mfma(const ushort* __restrict__ Ah,
                                                 const ushort* __restrict__ Al,
                                                 const ushort* __restrict__ Bh,
                                                 const ushort* __restrict__ Bl,
                                                 const float* __restrict__ bias,
                                                 _Float16* __restrict__ hp_out,
                                                 ushort* __restrict__ hh_out,
                                                 ushort* __restrict__ hl_out,
                                                 const float* __restrict__ att_s,
                                                 const float* __restrict__ att_d,
                                                 float* __restrict__ as_out,
                                                 float* __restrict__ ad_out,
                                                 int M, int K) {
    __shared__ __align__(16) ushort sAh[8192], sAl[8192], sBh[8192], sBl[8192];
    int tid = threadIdx.x;
    int m0 = blockIdx.x * 128, n0 = blockIdx.y * 128;
    int wid = tid >> 6, lane = tid & 63;
    int wm = wid & 1, wn = wid >> 1;
    int lr = lane & 15, grp = lane >> 4;
    f32x4 acc[4][4];
#pragma unroll
    for (int i = 0; i < 4; ++i)
#pragma unroll
        for (int j = 0; j < 4; ++j) acc[i][j] = (f32x4){0.f, 0.f, 0.f, 0.f};

    for (int k0 = 0; k0 < K; k0 += 64) {
        if (k0) __syncthreads();
#pragma unroll
        for (int i = 0; i < 4; ++i) {
            int ldso = wid * 2048 + i * 512;           // ushort units, wave-uniform
            int o = ldso + lane * 8;
            int m = o >> 6;                             // local row (64 ushorts/row)
            int kl = ((((o >> 3) & 7) ^ (m & 7)) << 3) + k0;
            size_t ga = (size_t)(m0 + m) * K + kl;
            size_t gb = (size_t)(n0 + m) * K + kl;
            g2l16(Ah + ga, sAh + ldso);
            g2l16(Al + ga, sAl + ldso);
            g2l16(Bh + gb, sBh + ldso);
            g2l16(Bl + gb, sBl + ldso);
        }
        __syncthreads();
#pragma unroll
        for (int ks = 0; ks < 2; ++ks) {
            bf16x8 vbh[4], vbl[4];
#pragma unroll
            for (int j = 0; j < 4; ++j) {
                int n = wn * 64 + j * 16 + lr;
                int off = n * 64 + ((ks * 32 + grp * 8) ^ ((n & 7) << 3));
                vbh[j] = *(const bf16x8*)&sBh[off];
                vbl[j] = *(const bf16x8*)&sBl[off];
            }
#pragma unroll
            for (int i = 0; i < 4; ++i) {
                int mm = wm * 64 + i * 16 + lr;
                int off = mm * 64 + ((ks * 32 + grp * 8) ^ ((mm & 7) << 3));
                bf16x8 vah = *(const bf16x8*)&sAh[off];
                bf16x8 valo = *(const bf16x8*)&sAl[off];
#pragma unroll
                for (int j = 0; j < 4; ++j) {
                    acc[i][j] = __builtin_amdgcn_mfma_f32_16x16x32_bf16(valo, vbh[j], acc[i][j], 0, 0, 0);
                    acc[i][j] = __builtin_amdgcn_mfma_f32_16x16x32_bf16(vah, vbl[j], acc[i][j], 0, 0, 0);
                    acc[i][j] = __builtin_amdgcn_mfma_f32_16x16x32_bf16(vah, vbh[j], acc[i][j], 0, 0, 0);
                }
            }
        }
    }
    // epilogue: C/D layout col=lane&15, row=(lane>>4)*4+reg [m89-verified]
#pragma unroll
    for (int j = 0; j < 4; ++j) {
        int c = n0 + wn * 64 + j * 16 + lr;
        float bj = (MODE == 0) ? bias[c] : 0.f;
#pragma unroll
        for (int i = 0; i < 4; ++i) {
            int mb = m0 + wm * 64 + i * 16 + grp * 4;
#pragma unroll
            for (int r = 0; r < 4; ++r) {
                int row = mb + r;
                if (row < M) {
                    float val = acc[i][j][r] + bj;
                    if (MODE == 0) {
                        union { float f; uint u; } uv; uv.f = val;
                        ushort hi = (ushort)(uv.u >> 16);
                        hh_out[(size_t)row * 256 + c] = hi;
                        hl_out[(size_t)row * 256 + c] = f2bf_rn(val - bf2f(hi));
                    } else {
                        hp_out[(size_t)row * 256 + c] = (_Float16)val;
                    }
                }
            }
        }
    }
    if (MODE == 1) {
        // fused a_s/a_d from f32 accumulators
        int h0 = (n0 >> 5) + wn * 2;   // first of this wave's two heads
        float as_w[4], ad_w[4];
#pragma unroll
        for (int j = 0; j < 4; ++j) {
            int h = h0 + (j >> 1);
            int cw = ((j & 1) << 4) + lr;
            as_w[j] = att_s[h * 32 + cw];
            ad_w[j] = att_d[h * 32 + cw];
        }
#pragma unroll
        for (int i = 0; i < 4; ++i) {
#pragma unroll
            for (int r = 0; r < 4; ++r) {
                float ps0 = acc[i][0][r] * as_w[0] + acc[i][1][r] * as_w[1];
                float ps1 = acc[i][2][r] * as_w[2] + acc[i][3][r] * as_w[3];
                float pd0 = acc[i][0][r] * ad_w[0] + acc[i][1][r] * ad_w[1];
                float pd1 = acc[i][2][r] * ad_w[2] + acc[i][3][r] * ad_w[3];
#pragma unroll
                for (int off = 1; off < 16; off <<= 1) {
                    ps0 += __shfl_xor(ps0, off);
                    ps1 += __shfl_xor(ps1, off);
                    pd0 += __shfl_xor(pd0, off);
                    pd1 += __shfl_xor(pd1, off);
                }
                if (lr == 0) {
                    int row = m0 + wm * 64 + i * 16 + grp * 4 + r;
                    if (row < M) {
                        as_out[row * 8 + h0]     = ps0;
                        as_out[row * 8 + h0 + 1] = ps1;
                        ad_out[row * 8 + h0]     = pd0;
                        ad_out[row * 8 + h0 + 1] = pd1;
                    }
                }
            }
        }
    }
}

// ---------------- aggregate ----------------

// one wave per dst node; pipelined e-phase + 16B/lane gather accumulation.
// LAST=1: fuse output projection (dot with w_out + wave reduce) -> out[n],
// skipping the h_hi/h_lo writes entirely.
template <int LAST>
__global__ __launch_bounds__(256) void aggregate_kernel(const _Float16* __restrict__ hp,
                                                        const float* __restrict__ a_s,
                                                        const float* __restrict__ a_d,
                                                        const _Float16* __restrict__ e_l,
                                                        const int* __restrict__ sorted_src,
                                                        const int* __restrict__ row_ptr,
                                                        const float* __restrict__ bias,
                                                        ushort* __restrict__ h_hi,
                                                        ushort* __restrict__ h_lo,
                                                        const float* __restrict__ w_out,
                                                        const float* __restrict__ b_out,
                                                        float* __restrict__ out) {
    int n = (blockIdx.x * 256 + threadIdx.x) >> 6;
    if (n >= NN) return;
    int lane = threadIdx.x & 63;
    int h1 = lane & 7;        // e-phase head
    int eslot = lane >> 3;    // e-phase edge slot
    int chan = lane & 31;     // accum: channels chan*8..chan*8+7 (16B fp16)
    int half = lane >> 5;     // accum: 0 -> even slots, 1 -> odd slots
    int hh = chan >> 2;       // head of owned channels
    int beg = row_ptr[n], end = row_ptr[n + 1];   // deg >= 1 (self-loop)
    float ad1 = a_d[n * 8 + h1];
    float s = 0.f;
    float acc[8] = {};

    // prologue: load batch 0 inputs
    int j0 = beg + eslot;
    bool valid = j0 < end;
    int jc = valid ? j0 : (end - 1);
    int srce = sorted_src[jc];
    float asv = a_s[srce * 8 + h1];
    float elv = (float)e_l[(size_t)jc * 8 + h1];

    for (int base = beg; base < end; base += 8) {
        // prefetch next batch (overlaps with current batch's gather+FMA)
        int srce_n = 0; float asn = 0.f, eln = 0.f; bool nvalid = false;
        int nbase = base + 8;
        if (nbase < end) {
            int nj = nbase + eslot;
            nvalid = nj < end;
            int njc = nvalid ? nj : (end - 1);
            srce_n = sorted_src[njc];
            asn = a_s[srce_n * 8 + h1];
            eln = (float)e_l[(size_t)njc * 8 + h1];
        }
        // current batch weight
        float e = asv + ad1 + elv;
        e = (e >= 0.f) ? e : NEG_SLOPE * e;
        float w1 = valid ? __expf(e) : 0.f;
        // each half processes 4 of the 8 slots: slot = p*2 + half
        float wv[4];
        int sv[4];
#pragma unroll
        for (int p = 0; p < 4; ++p) {
            int slot = p * 2 + half;
            wv[p] = __shfl(w1, slot * 8 + hh);
            sv[p] = __shfl(srce, slot * 8);
        }
        union { uint4 u; _Float16 q[8]; } hv[4];
#pragma unroll
        for (int p = 0; p < 4; ++p)
            hv[p].u = *(const uint4*)&hp[(size_t)sv[p] * 256 + chan * 8];
#pragma unroll
        for (int p = 0; p < 4; ++p) {
            float w = wv[p];
            s += w;
#pragma unroll
            for (int k = 0; k < 8; ++k) acc[k] += w * (float)hv[p].q[k];
        }
        // rotate pipeline
        srce = srce_n; asv = asn; elv = eln; valid = nvalid;
    }
    // merge the two halves (lane ^ 32 owns same channels, other slot parity)
    s += __shfl_xor(s, 32);
#pragma unroll
    for (int k = 0; k < 8; ++k) acc[k] += __shfl_xor(acc[k], 32);

    float inv = 1.0f / (s + 1e-16f);
    const float4* b4 = (const float4*)&bias[chan * 8];
    float4 bA = b4[0], bB = b4[1];
    float o[8];
    o[0] = acc[0] * inv + bA.x; o[1] = acc[1] * inv + bA.y;
    o[2] = acc[2] * inv + bA.z; o[3] = acc[3] * inv + bA.w;
    o[4] = acc[4] * inv + bB.x; o[5] = acc[5] * inv + bB.y;
    o[6] = acc[6] * inv + bB.z; o[7] = acc[7] * inv + bB.w;
    if (LAST) {
        // fused output projection: both halves hold the full row; reduce 32 lanes
        const float4* w4 = (const float4*)&w_out[chan * 8];
        float4 wA = w4[0], wB = w4[1];
        float dot = o[0] * wA.x + o[1] * wA.y + o[2] * wA.z + o[3] * wA.w +
                    o[4] * wB.x + o[5] * wB.y + o[6] * wB.z + o[7] * wB.w;
        for (int off = 1; off < 32; off <<= 1) dot += __shfl_xor(dot, off);
        if (lane == 0) out[n] = dot + b_out[0];
        return;
    }
    union { uint4 u; ushort v[8]; } pk;
    if (half == 0) {
#pragma unroll
        for (int k = 0; k < 8; ++k) {
            union { float f; uint u; } uv; uv.f = o[k];
            pk.v[k] = (ushort)(uv.u >> 16);
        }
        *(uint4*)&h_hi[(size_t)n * 256 + chan * 8] = pk.u;
    } else {
#pragma unroll
        for (int k = 0; k < 8; ++k) {
            union { float f; uint u; } uv; uv.f = o[k];
            ushort hi = (ushort)(uv.u >> 16);
            pk.v[k] = f2bf_rn(o[k] - bf2f(hi));
        }
        *(uint4*)&h_lo[(size_t)n * 256 + chan * 8] = pk.u;
    }
}

// ---------------- launch ----------------

extern "C" void kernel_launch(void* const* d_in, const int* in_sizes, int n_in,
                              void* d_out, int out_size, void* d_ws, size_t ws_size,
                              hipStream_t stream) {
    const float* x         = (const float*)d_in[0];
    const int*   edge_idx  = (const int*)d_in[1];
    const float* edge_attr = (const float*)d_in[2];
    const float* w_in      = (const float*)d_in[3];
    const float* b_in      = (const float*)d_in[4];
    const float* W_l       = (const float*)d_in[5];
    const float* We_l      = (const float*)d_in[6];
    const float* att_src   = (const float*)d_in[7];
    const float* att_dst   = (const float*)d_in[8];
    const float* att_edge  = (const float*)d_in[9];
    const float* bias_l    = (const float*)d_in[10];
    const float* w_out     = (const float*)d_in[11];
    const float* b_out     = (const float*)d_in[12];
    float* out = (float*)d_out;

    char* ws = (char*)d_ws;
    size_t off = 0;
    auto alloc = [&](size_t bytes) -> void* {
        void* p = ws + off;
        off = (off + bytes + 255) & ~(size_t)255;
        return p;
    };
    ushort*   h_hi       = (ushort*)alloc((size_t)MPAD * 256 * 2);
    ushort*   h_lo       = (ushort*)alloc((size_t)MPAD * 256 * 2);
    _Float16* hp16       = (_Float16*)alloc((size_t)MPAD * 256 * 2);
    float*    a_s        = (float*)alloc((size_t)NN * 8 * 4);
    float*    a_d        = (float*)alloc((size_t)NN * 8 * 4);
    int*      sorted_src = (int*)alloc((size_t)ETOT * 4);
    int*      sorted_eid = (int*)alloc((size_t)ETOT * 4);
    int*      row_ptr    = (int*)alloc((size_t)(NN + 1) * 4);
    int*      fill       = (int*)alloc((size_t)NN * 4);
    int*      cnt        = (int*)alloc((size_t)NN * 4);
    int*      bsum       = (int*)alloc(64 * 4);
    float*    col_part   = (float*)alloc((size_t)1024 * 32 * 4);
    float*    mean_ea    = (float*)alloc(32 * 4);
    float*    v          = (float*)alloc(1024 * 4);
    ushort*   bsp_hi     = (ushort*)alloc((size_t)294912 * 2);
    ushort*   bsp_lo     = (ushort*)alloc((size_t)294912 * 2);
    // union region: {xh, xl} then (after input GEMM) e_all overlays it
    char*     uni        = (char*)alloc((size_t)4 * ETOT * 8 * 2);  // 54.4 MB
    ushort*   xh         = (ushort*)uni;
    ushort*   xl         = (ushort*)(uni + (size_t)MPAD * 128 * 2);
    _Float16* e_all      = (_Float16*)uni;

    const int NB = (NN + 1023) / 1024;  // 49

    // weight prep + input projection (uses xh/xl before e_all overlays)
    zero_int_kernel<<<(NN + 255) / 256, 256, 0, stream>>>(cnt, NN);
    precompute_kernel<<<1, 1024, 0, stream>>>(We_l, att_edge, v);
    col_partial<<<1024, 256, 0, stream>>>(edge_attr, col_part);
    col_final<<<1, 256, 0, stream>>>(col_part, mean_ea);
    split_weights<<<(294912 + 255) / 256, 256, 0, stream>>>(w_in, W_l, bsp_hi, bsp_lo);
    split_x<<<(MPAD * 128 + 255) / 256, 256, 0, stream>>>(x, xh, xl);

    dim3 ggrid((NN + 127) / 128, 2);
    gemm_mfma<0><<<ggrid, 256, 0, stream>>>(xh, xl, bsp_hi, bsp_lo, b_in,
                                            nullptr, h_hi, h_lo,
                                            nullptr, nullptr, nullptr, nullptr,
                                            NN, IN_DIM);

    // graph build + all-layer edge logits (e_all overlays xh/xl — input GEMM done)
    hist_kernel<<<(ETOT + 255) / 256, 256, 0, stream>>>(edge_idx, cnt);
    scan_phase1<<<NB, 256, 0, stream>>>(cnt, bsum);
    scan_phase2<<<1, 64, 0, stream>>>(bsum, row_ptr, NB);
    scan_phase3<<<NB, 256, 0, stream>>>(cnt, bsum, row_ptr, fill);
    scatter_kernel<<<(ETOT + 255) / 256, 256, 0, stream>>>(edge_idx, fill, sorted_src, sorted_eid);
    edge_logits<<<(ETOT + 255) / 256, 256, 0, stream>>>(edge_attr, mean_ea, sorted_eid, v, e_all);

    for (int l = 0; l < LL; ++l) {
        const ushort* wh = bsp_hi + 32768 + (size_t)l * 65536;
        const ushort* wl = bsp_lo + 32768 + (size_t)l * 65536;
        gemm_mfma<1><<<ggrid, 256, 0, stream>>>(h_hi, h_lo, wh, wl, nullptr,
                                                hp16, nullptr, nullptr,
                                                att_src + l * 256, att_dst + l * 256,
                                                a_s, a_d, NN, EMB);
        if (l < LL - 1) {
            aggregate_kernel<0><<<NN / 4, 256, 0, stream>>>(
                hp16, a_s, a_d, e_all + (size_t)l * ETOT * 8, sorted_src, row_ptr,
                bias_l + l * 256, h_hi, h_lo, nullptr, nullptr, nullptr);
        } else {
            aggregate_kernel<1><<<NN / 4, 256, 0, stream>>>(
                hp16, a_s, a_d, e_all + (size_t)l * ETOT * 8, sorted_src, row_ptr,
                bias_l + l * 256, nullptr, nullptr, w_out, b_out, out);
        }
    }
}